// Round 1
// 389.610 us; speedup vs baseline: 18.6883x; 18.6883x over previous
//
#include <hip/hip_runtime.h>
#include <hip/hip_fp16.h>
#include <math.h>

#define T_ 1024
#define B_ 512
#define I_ 128
#define H_ 256
#define K_ 384   /* I_ + H_ */
#define KP_ 192  /* k-pairs */

typedef _Float16 h2_t __attribute__((ext_vector_type(2)));

__device__ __forceinline__ float fsigmoid(float x) {
  return 1.0f / (1.0f + __expf(-x));
}
__device__ __forceinline__ float ftanh(float x) {
  float ax = fabsf(x);
  float e = __expf(-2.0f * ax);  // in (0,1], no overflow
  float t = (1.0f - e) / (1.0f + e);
  return copysignf(t, x);
}
// acc += dot2(fp16 pair w, fp16 pair v)  -> v_dot2_f32_f16
__device__ __forceinline__ void dot2(float& acc, unsigned int w, unsigned int v) {
  acc = __builtin_amdgcn_fdot2(__builtin_bit_cast(h2_t, w),
                               __builtin_bit_cast(h2_t, v), acc, false);
}

// ---------------------------------------------------------------------------
// Pack fused fp32 weights [W_ih | W_hh] into fp16 gate-quads:
//   Whq[(kp*H_ + j)*8 + g*2 + d] = (half) W_fused[g*H_ + j][2kp + d]
// One uint4 = 4 gates x 2 k's for unit j, k-pair kp.
// ---------------------------------------------------------------------------
__global__ void prep_kernel(const float* __restrict__ W_ih,
                            const float* __restrict__ W_hh,
                            const float* __restrict__ b_ih,
                            const float* __restrict__ b_hh,
                            __half* __restrict__ Whq,
                            float4* __restrict__ biasq) {
  const int j = (int)threadIdx.x;   // 0..255
  const int kp = (int)blockIdx.x;   // 0..191
  const int k0 = 2 * kp, k1 = 2 * kp + 1;
  __half* dst = Whq + ((size_t)(kp * H_ + j)) * 8;
#pragma unroll
  for (int g = 0; g < 4; ++g) {
    const int row = g * H_ + j;
    float w0, w1;
    if (k0 < I_) {
      w0 = W_ih[row * I_ + k0];
      w1 = W_ih[row * I_ + k1];
    } else {
      w0 = W_hh[row * H_ + (k0 - I_)];
      w1 = W_hh[row * H_ + (k1 - I_)];
    }
    dst[g * 2 + 0] = __float2half(w0);
    dst[g * 2 + 1] = __float2half(w1);
  }
  if (kp == 0) {
    biasq[j] = make_float4(b_ih[j] + b_hh[j],
                           b_ih[H_ + j] + b_hh[H_ + j],
                           b_ih[2 * H_ + j] + b_hh[2 * H_ + j],
                           b_ih[3 * H_ + j] + b_hh[3 * H_ + j]);
  }
}

// ---------------------------------------------------------------------------
// Main kernel: grid 256 x 1024 threads. Block handles batches {2b, 2b+1}.
//
// KEY SHORTCUT (exact, input-dependent runtime): the recurrence carry is
// (m*h, m*c) with m in {0,1}; when m==0 the state is EXACTLY zeroed.  The
// only consumed output is the unmasked h_new at t=T-1, so per batch the
// result depends only on steps after the last reset
//   s_b = 1 + max{ t <= T-2 : x[t,b,I-1] <= 0 }   (0 if no reset).
// Starting a batch at ANY t <= s_b with zero state is exact (its own m==0
// step re-zeroes the state), so the block starts at min(s_b0, s_b1).
//
// Thread (kq = tid>>8 in 0..3, j = tid&255):
//   dot phase : v_dot2_f32_f16 partial gate sums for BOTH batches over
//               k-quarter kq (weights loaded once, fp16, no duplication)
//   act phase : threads kq<2 finalize batch kq, unit j after 4-way LDS
//               partial exchange.
// ---------------------------------------------------------------------------
__global__ __launch_bounds__(1024) void lstm_kernel(
    const float* __restrict__ x,      // [T,B,I] fp32
    const uint4* __restrict__ W4,     // [KP_*H_] packed fp16 gate-quads
    const float4* __restrict__ biasq, // [H_]
    const float* __restrict__ W_out,  // [H_]
    const float* __restrict__ b_out,  // [1]
    float* __restrict__ out) {        // [B_]
  __shared__ __align__(16) __half v[2][K_];        // [x_t ; h] fp16 per batch
  __shared__ __align__(16) float4 part[4][2][H_];  // [kq][batch][j]
  __shared__ float msk[2];
  __shared__ float red[8];
  __shared__ int sred[16];
  __shared__ int sstart_sh;
  const int tid = (int)threadIdx.x;
  const int kq = tid >> 8;       // k-quarter (dot) / batch (act, if <2)
  const int j = tid & (H_ - 1);  // hidden unit
  const int b0 = (int)blockIdx.x * 2;

  const float4 bias = biasq[j];

  // ---- mask scan: find last reset per batch, block start = min ----
  {
    const int sb2 = tid >> 9;        // batch 0/1 (512 threads each)
    const int idx = tid & 511;
    const long base = (long)(b0 + sb2) * I_ + (I_ - 1);
    int best = 0;
    {  // t = idx in [0,511], always <= T_-2
      const float xv = x[base + (long)idx * ((long)B_ * I_)];
      if (xv <= 0.0f) best = idx + 1;
    }
    if (idx + 512 <= T_ - 2) {  // t = idx+512 in [512,1022]
      const float xv = x[base + (long)(idx + 512) * ((long)B_ * I_)];
      if (xv <= 0.0f) best = idx + 513;  // > idx+1, plain overwrite is max
    }
#pragma unroll
    for (int off = 32; off > 0; off >>= 1) {
      const int o = __shfl_down(best, off, 64);
      best = best > o ? best : o;
    }
    const int wave = tid >> 6;
    if ((tid & 63) == 0) sred[wave] = best;
  }
  __syncthreads();
  if (tid == 0) {
    int s0 = 0, s1 = 0;
#pragma unroll
    for (int w = 0; w < 8; ++w) {
      s0 = max(s0, sred[w]);
      s1 = max(s1, sred[8 + w]);
    }
    sstart_sh = min(s0, s1);
  }
  __syncthreads();
  const int ts = sstart_sh;

  // init: h0 = 0 (fp16), stage x for t=ts, mask for t=ts
  if (kq < 2) v[kq][I_ + j] = __float2half(0.0f);
  if (tid < 2 * I_) {
    const int sb = tid >> 7, ii = tid & (I_ - 1);
    const float xv = x[((long)ts * B_ + (b0 + sb)) * I_ + ii];
    v[sb][ii] = __float2half(xv);
    if (ii == I_ - 1) msk[sb] = (xv > 0.0f) ? 1.0f : 0.0f;
  }

  float c = 0.0f, lasth = 0.0f;
  const uint4* __restrict__ wbase = W4 + (size_t)(kq * (KP_ / 4)) * H_ + j;
  const uint4* __restrict__ v0q = (const uint4*)(&v[0][kq * (K_ / 4)]);
  const uint4* __restrict__ v1q = (const uint4*)(&v[1][kq * (K_ / 4)]);

  for (int t = ts; t < T_; ++t) {
    __syncthreads();  // (A) x_t, h_{t-1}, msk visible
    float m = 0.0f;
    if (kq < 2) m = msk[kq];  // read BEFORE next staging overwrites it

    float4 acc0 = make_float4(0.f, 0.f, 0.f, 0.f);
    float4 acc1 = make_float4(0.f, 0.f, 0.f, 0.f);
    const uint4* wp = wbase;
#pragma unroll 4
    for (int i = 0; i < 12; ++i) {  // 8 k's per iter
      const uint4 va = v0q[i];      // 8 fp16 of [x;h], batch 0 (LDS broadcast)
      const uint4 vb = v1q[i];      // batch 1
      const uint4 w0 = wp[0];       // gate-quad, k-pair 4i+0
      const uint4 w1 = wp[H_];      // 4i+1
      const uint4 w2 = wp[2 * H_];  // 4i+2
      const uint4 w3 = wp[3 * H_];  // 4i+3
      wp += 4 * H_;
      dot2(acc0.x, w0.x, va.x); dot2(acc0.y, w0.y, va.x);
      dot2(acc0.z, w0.z, va.x); dot2(acc0.w, w0.w, va.x);
      dot2(acc1.x, w0.x, vb.x); dot2(acc1.y, w0.y, vb.x);
      dot2(acc1.z, w0.z, vb.x); dot2(acc1.w, w0.w, vb.x);
      dot2(acc0.x, w1.x, va.y); dot2(acc0.y, w1.y, va.y);
      dot2(acc0.z, w1.z, va.y); dot2(acc0.w, w1.w, va.y);
      dot2(acc1.x, w1.x, vb.y); dot2(acc1.y, w1.y, vb.y);
      dot2(acc1.z, w1.z, vb.y); dot2(acc1.w, w1.w, vb.y);
      dot2(acc0.x, w2.x, va.z); dot2(acc0.y, w2.y, va.z);
      dot2(acc0.z, w2.z, va.z); dot2(acc0.w, w2.w, va.z);
      dot2(acc1.x, w2.x, vb.z); dot2(acc1.y, w2.y, vb.z);
      dot2(acc1.z, w2.z, vb.z); dot2(acc1.w, w2.w, vb.z);
      dot2(acc0.x, w3.x, va.w); dot2(acc0.y, w3.y, va.w);
      dot2(acc0.z, w3.z, va.w); dot2(acc0.w, w3.w, va.w);
      dot2(acc1.x, w3.x, vb.w); dot2(acc1.y, w3.y, vb.w);
      dot2(acc1.z, w3.z, vb.w); dot2(acc1.w, w3.w, vb.w);
    }
    part[kq][0][j] = acc0;
    part[kq][1][j] = acc1;
    __syncthreads();  // (B) partials visible; all v/msk reads done

    if (kq < 2) {  // act phase: batch kq, unit j
      const float4 p0 = part[0][kq][j];
      const float4 p1 = part[1][kq][j];
      const float4 p2 = part[2][kq][j];
      const float4 p3 = part[3][kq][j];
      const float gi = fsigmoid(p0.x + p1.x + p2.x + p3.x + bias.x);
      const float gf = fsigmoid(p0.y + p1.y + p2.y + p3.y + bias.y);
      const float gg = ftanh(p0.z + p1.z + p2.z + p3.z + bias.z);
      const float go = fsigmoid(p0.w + p1.w + p2.w + p3.w + bias.w);
      const float cn = gf * c + gi * gg;
      const float hn = go * ftanh(cn);
      if (t == T_ - 1) lasth = hn;  // hs[-1] is the UNMASKED h_new
      c = m * cn;
      v[kq][I_ + j] = __float2half(m * hn);  // h carry (masked)
    }
    if (t + 1 < T_ && tid < 2 * I_) {  // stage x_{t+1} + its mask
      const int sb = tid >> 7, ii = tid & (I_ - 1);
      const float xv = x[((long)(t + 1) * B_ + (b0 + sb)) * I_ + ii];
      v[sb][ii] = __float2half(xv);
      if (ii == I_ - 1) msk[sb] = (xv > 0.0f) ? 1.0f : 0.0f;
    }
  }

  // likelihood[b0+bb] = sum_j W_out[j] * lasth + b_out   (threads kq<2 only)
  float p = (kq < 2) ? W_out[j] * lasth : 0.0f;
#pragma unroll
  for (int off = 32; off > 0; off >>= 1) p += __shfl_down(p, off, 64);
  const int wave = tid >> 6;
  if (wave < 8 && (tid & 63) == 0) red[wave] = p;
  __syncthreads();
  if (tid == 0)   out[b0]     = red[0] + red[1] + red[2] + red[3] + b_out[0];
  if (tid == 256) out[b0 + 1] = red[4] + red[5] + red[6] + red[7] + b_out[0];
}

extern "C" void kernel_launch(void* const* d_in, const int* in_sizes, int n_in,
                              void* d_out, int out_size, void* d_ws, size_t ws_size,
                              hipStream_t stream) {
  (void)in_sizes; (void)n_in; (void)out_size; (void)ws_size;
  const float* x     = (const float*)d_in[0];  // [T,B,I]
  const float* W_ih  = (const float*)d_in[1];  // [4H,I]
  const float* W_hh  = (const float*)d_in[2];  // [4H,H]
  const float* b_ih  = (const float*)d_in[3];  // [4H]
  const float* b_hh  = (const float*)d_in[4];  // [4H]
  const float* W_out = (const float*)d_in[5];  // [1,H]
  const float* b_out = (const float*)d_in[6];  // [1]
  float* out = (float*)d_out;                  // [B]

  __half* Whq   = (__half*)d_ws;  // 192*256*8 halves = 786,432 B
  float4* biasq = (float4*)((char*)d_ws + (size_t)KP_ * H_ * 8 * sizeof(__half));

  hipLaunchKernelGGL(prep_kernel, dim3(KP_), dim3(H_), 0, stream,
                     W_ih, W_hh, b_ih, b_hh, Whq, biasq);
  hipLaunchKernelGGL(lstm_kernel, dim3(B_ / 2), dim3(1024), 0, stream,
                     x, (const uint4*)Whq, biasq, W_out, b_out, out);
}